// Round 1
// baseline (1672.697 us; speedup 1.0000x reference)
//
#include <hip/hip_runtime.h>
#include <math.h>

// Problem constants
#define BATCH   8
#define SEQ     512
#define HID     2048
#define NH      32
#define NKV     8
#define HD      64
#define MROWS   4096            // BATCH*SEQ
#define NQKV    3072            // 2048 Q + 512 K + 512 V
#define SCALE   0.125f          // 1/sqrt(64)

// ---------------------------------------------------------------------------
// GEMM: C[M x N] = A[M x K] * W[K x N], fp32 vector-ALU.
// Tile 128x128, BK=16, 256 threads, 8x8 per thread as 2x2 quadrants of 4x4.
// As row stride 20 floats (pad 4): compute-phase a-loads are 2-way conflicts.
// Bs row stride 128: b-loads stride 16B across tx -> 2-way. Both free (m136).
// ---------------------------------------------------------------------------
struct GemmSmem {
  float As[128 * 20];
  float Bs[16 * 128];
};

__device__ __forceinline__ void gemm_tile_compute(
    const float* __restrict__ A, int lda,
    const float* __restrict__ Bm, int ldb, int nb,
    int mtile, int K,
    float acc[2][2][4][4], GemmSmem& sm)
{
  const int tid = threadIdx.x;
  const int tx = tid & 15, ty = tid >> 4;

  for (int kt = 0; kt < K; kt += 16) {
    // Stage A (128x16) and B (16x128): 2 float4 each per thread
    #pragma unroll
    for (int p = 0; p < 2; p++) {
      int e = tid * 2 + p;
      int r  = e >> 2, k4 = (e & 3) * 4;
      *(float4*)(&sm.As[r * 20 + k4]) =
          *(const float4*)(&A[(size_t)(mtile + r) * lda + kt + k4]);
      int kk = e >> 5, c4 = (e & 31) * 4;
      *(float4*)(&sm.Bs[kk * 128 + c4]) =
          *(const float4*)(&Bm[(size_t)(kt + kk) * ldb + nb + c4]);
    }
    __syncthreads();

    #pragma unroll
    for (int k4 = 0; k4 < 4; k4++) {
      float4 a[2][4], bv[2][4];
      #pragma unroll
      for (int g = 0; g < 2; g++)
        #pragma unroll
        for (int i = 0; i < 4; i++)
          a[g][i] = *(float4*)(&sm.As[(g * 64 + ty * 4 + i) * 20 + k4 * 4]);
      #pragma unroll
      for (int g = 0; g < 2; g++)
        #pragma unroll
        for (int k = 0; k < 4; k++)
          bv[g][k] = *(float4*)(&sm.Bs[(k4 * 4 + k) * 128 + g * 64 + tx * 4]);
      #pragma unroll
      for (int gr = 0; gr < 2; gr++)
        #pragma unroll
        for (int i = 0; i < 4; i++) {
          float ak[4] = {a[gr][i].x, a[gr][i].y, a[gr][i].z, a[gr][i].w};
          #pragma unroll
          for (int k = 0; k < 4; k++)
            #pragma unroll
            for (int gc = 0; gc < 2; gc++) {
              acc[gr][gc][i][0] += ak[k] * bv[gc][k].x;
              acc[gr][gc][i][1] += ak[k] * bv[gc][k].y;
              acc[gr][gc][i][2] += ak[k] * bv[gc][k].z;
              acc[gr][gc][i][3] += ak[k] * bv[gc][k].w;
            }
        }
    }
    __syncthreads();
  }
}

// Fused Q/K/V projection. Column tiles 0..15 -> Q (ws), 16..19 -> K (ws),
// 20..23 -> V written directly to d_out v-cache in [B,HKV,S,D] layout.
__global__ __launch_bounds__(256, 2)
void gemm_qkv(const float* __restrict__ x,
              const float* __restrict__ Wq,
              const float* __restrict__ Wk,
              const float* __restrict__ Wv,
              float* __restrict__ Qws, float* __restrict__ Kws,
              float* __restrict__ vout)
{
  __shared__ GemmSmem sm;
  const int ntile = blockIdx.x * 128;   // 0..3071
  const int mtile = blockIdx.y * 128;

  const float* Bm; int ldb, nb;
  if (ntile < 2048)      { Bm = Wq; ldb = 2048; nb = ntile; }
  else if (ntile < 2560) { Bm = Wk; ldb = 512;  nb = ntile - 2048; }
  else                   { Bm = Wv; ldb = 512;  nb = ntile - 2560; }

  float acc[2][2][4][4] = {};
  gemm_tile_compute(x, HID, Bm, ldb, nb, mtile, HID, acc, sm);

  const int tx = threadIdx.x & 15, ty = threadIdx.x >> 4;
  #pragma unroll
  for (int gr = 0; gr < 2; gr++)
    #pragma unroll
    for (int i = 0; i < 4; i++) {
      int m = mtile + gr * 64 + ty * 4 + i;
      int bb = m >> 9, s = m & 511;
      #pragma unroll
      for (int gc = 0; gc < 2; gc++) {
        int n = ntile + gc * 64 + tx * 4;
        float4 v = make_float4(acc[gr][gc][i][0], acc[gr][gc][i][1],
                               acc[gr][gc][i][2], acc[gr][gc][i][3]);
        if (n < 2048) {
          *(float4*)(&Qws[(size_t)m * 2048 + n]) = v;
        } else if (n < 2560) {
          *(float4*)(&Kws[(size_t)m * 512 + (n - 2048)]) = v;
        } else {
          int np = n - 2560; int hk = np >> 6; int d = np & 63;
          *(float4*)(&vout[((size_t)((bb * 8 + hk) * 512 + s)) * 64 + d]) = v;
        }
      }
    }
}

// Output projection: out = Attn[4096,2048] @ Wo[2048,2048]
__global__ __launch_bounds__(256, 2)
void gemm_out(const float* __restrict__ Attn, const float* __restrict__ Wo,
              float* __restrict__ Cout)
{
  __shared__ GemmSmem sm;
  const int ntile = blockIdx.x * 128;
  const int mtile = blockIdx.y * 128;
  float acc[2][2][4][4] = {};
  gemm_tile_compute(Attn, HID, Wo, HID, ntile, mtile, HID, acc, sm);

  const int tx = threadIdx.x & 15, ty = threadIdx.x >> 4;
  #pragma unroll
  for (int gr = 0; gr < 2; gr++)
    #pragma unroll
    for (int i = 0; i < 4; i++) {
      int m = mtile + gr * 64 + ty * 4 + i;
      #pragma unroll
      for (int gc = 0; gc < 2; gc++) {
        int n = ntile + gc * 64 + tx * 4;
        float4 v = make_float4(acc[gr][gc][i][0], acc[gr][gc][i][1],
                               acc[gr][gc][i][2], acc[gr][gc][i][3]);
        *(float4*)(&Cout[(size_t)m * 2048 + n]) = v;
      }
    }
}

// RoPE on Q, in place in [B,S,H*D] layout. One thread per (d, d+32) pair.
__global__ void rope_q(float* __restrict__ Q)
{
  int idx = blockIdx.x * 256 + threadIdx.x;     // 4096*1024 threads
  int m = idx >> 10; int r = idx & 1023;
  int h = r >> 5;    int i = r & 31;
  int s = m & 511;
  float inv = powf(10000.0f, -(float)i * (1.0f / 32.0f));
  float th = (float)s * inv;
  float sn, cs; sincosf(th, &sn, &cs);
  float* p = Q + (size_t)m * 2048 + h * 64 + i;
  float q0 = p[0], q1 = p[32];
  p[0]  = q0 * cs - q1 * sn;
  p[32] = q1 * cs + q0 * sn;
}

// RoPE on K, scratch [B,S,HKV*D] -> d_out k-cache [B,HKV,S,D]
__global__ void rope_k(const float* __restrict__ Kws, float* __restrict__ kout)
{
  int idx = blockIdx.x * 256 + threadIdx.x;     // 4096*256 threads
  int m = idx >> 8; int r = idx & 255;
  int hk = r >> 5;  int i = r & 31;
  int bb = m >> 9, s = m & 511;
  float inv = powf(10000.0f, -(float)i * (1.0f / 32.0f));
  float th = (float)s * inv;
  float sn, cs; sincosf(th, &sn, &cs);
  const float* p = Kws + (size_t)m * 512 + hk * 64 + i;
  float k0 = p[0], k1 = p[32];
  float* o = kout + ((size_t)((bb * 8 + hk) * 512 + s)) * 64 + i;
  o[0]  = k0 * cs - k1 * sn;
  o[32] = k1 * cs + k0 * sn;
}

// ---------------------------------------------------------------------------
// Flash-style causal GQA attention, fp32.
// Block = (qt, h, b): 64 q-rows x full kv (tiles of 64). 256 threads.
// Thread (ty,tx): S rows 4ty+i, S cols tx+16c (stride-16 ownership keeps
// the K-row ds_read_b128 at 2-way conflicts); O rows 4ty+i, cols 4tx+j.
// P-buffer aliases the K-buffer (extra barrier) to fit 64KB static LDS.
// Online softmax: 4 lanes per row + shfl_xor (no serial-lane softmax).
// ---------------------------------------------------------------------------
#define RS 68   // padded LDS row stride (floats); RS % 8 == 4

__global__ __launch_bounds__(256, 2)
void attn(const float* __restrict__ Qws, const float* __restrict__ kc,
          const float* __restrict__ vc, float* __restrict__ Aout)
{
  __shared__ float Qs[64 * RS];
  __shared__ float KPs[64 * RS];   // K tile, then reused as P tile
  __shared__ float Vs[64 * 64];
  __shared__ float rowscale[64], rowsum[64];

  const int qt = blockIdx.x, h = blockIdx.y, bb = blockIdx.z;
  const int hk = h >> 2;
  const int tid = threadIdx.x;
  const int tx = tid & 15, ty = tid >> 4;
  const int sr = tid >> 2, sg = tid & 3;

  // Stage Q tile (64 x 64) from [B,S,H*D]
  const float* qbase = Qws + ((size_t)(bb * 512 + qt * 64)) * 2048 + h * 64;
  #pragma unroll
  for (int i0 = 0; i0 < 4; i0++) {
    int e = tid + 256 * i0;
    int r = e >> 4, d4 = (e & 15) * 4;
    *(float4*)(&Qs[r * RS + d4]) = *(const float4*)(&qbase[(size_t)r * 2048 + d4]);
  }

  float acc[4][4] = {};
  float m_r = -1e30f, l_r = 0.0f;
  const size_t kvbase = ((size_t)(bb * 8 + hk)) * 512 * 64;

  for (int j = 0; j <= qt; j++) {
    __syncthreads();   // prev PV reads done; also covers Q staging on iter 0
    const float* kb = kc + kvbase + (size_t)j * 64 * 64;
    const float* vb = vc + kvbase + (size_t)j * 64 * 64;
    #pragma unroll
    for (int i0 = 0; i0 < 4; i0++) {
      int e = tid + 256 * i0;
      int r = e >> 4, d4 = (e & 15) * 4;
      *(float4*)(&KPs[r * RS + d4]) = *(const float4*)(&kb[r * 64 + d4]);
      *(float4*)(&Vs[r * 64 + d4])  = *(const float4*)(&vb[r * 64 + d4]);
    }
    __syncthreads();

    // S = Q K^T
    float sacc[4][4] = {};
    #pragma unroll
    for (int k4 = 0; k4 < 16; k4++) {
      float4 qa[4], ka[4];
      #pragma unroll
      for (int i = 0; i < 4; i++) qa[i] = *(float4*)(&Qs[(ty * 4 + i) * RS + k4 * 4]);
      #pragma unroll
      for (int c = 0; c < 4; c++) ka[c] = *(float4*)(&KPs[(tx + 16 * c) * RS + k4 * 4]);
      #pragma unroll
      for (int i = 0; i < 4; i++)
        #pragma unroll
        for (int c = 0; c < 4; c++)
          sacc[i][c] += qa[i].x * ka[c].x + qa[i].y * ka[c].y +
                        qa[i].z * ka[c].z + qa[i].w * ka[c].w;
    }
    __syncthreads();   // all K reads done before P overwrites the buffer

    // scale + causal mask, write P into KPs
    #pragma unroll
    for (int i = 0; i < 4; i++) {
      int qg = qt * 64 + ty * 4 + i;
      #pragma unroll
      for (int c = 0; c < 4; c++) {
        int kg = j * 64 + tx + 16 * c;
        float sv = sacc[i][c] * SCALE;
        if (kg > qg) sv = -1e30f;
        KPs[(ty * 4 + i) * RS + tx + 16 * c] = sv;
      }
    }
    __syncthreads();

    // Online softmax: thread (sr,sg) owns row sr, cols 16sg..16sg+15
    float4 pv[4];
    float tm = -1e30f;
    #pragma unroll
    for (int c4 = 0; c4 < 4; c4++) {
      pv[c4] = *(float4*)(&KPs[sr * RS + sg * 16 + c4 * 4]);
      tm = fmaxf(tm, fmaxf(fmaxf(pv[c4].x, pv[c4].y), fmaxf(pv[c4].z, pv[c4].w)));
    }
    tm = fmaxf(tm, __shfl_xor(tm, 1));
    tm = fmaxf(tm, __shfl_xor(tm, 2));
    float mnew = fmaxf(m_r, tm);
    float sc_old = __expf(m_r - mnew);
    float lsum = 0.0f;
    #pragma unroll
    for (int c4 = 0; c4 < 4; c4++) {
      pv[c4].x = __expf(pv[c4].x - mnew);
      pv[c4].y = __expf(pv[c4].y - mnew);
      pv[c4].z = __expf(pv[c4].z - mnew);
      pv[c4].w = __expf(pv[c4].w - mnew);
      lsum += pv[c4].x + pv[c4].y + pv[c4].z + pv[c4].w;
      *(float4*)(&KPs[sr * RS + sg * 16 + c4 * 4]) = pv[c4];
    }
    lsum += __shfl_xor(lsum, 1);
    lsum += __shfl_xor(lsum, 2);
    l_r = l_r * sc_old + lsum;
    m_r = mnew;
    if (sg == 0) { rowscale[sr] = sc_old; rowsum[sr] = l_r; }
    __syncthreads();

    // O = O * rowscale + P @ V
    #pragma unroll
    for (int i = 0; i < 4; i++) {
      float rsc = rowscale[ty * 4 + i];
      #pragma unroll
      for (int jj = 0; jj < 4; jj++) acc[i][jj] *= rsc;
    }
    #pragma unroll
    for (int k4 = 0; k4 < 16; k4++) {
      float4 pa[4], va[4];
      #pragma unroll
      for (int i = 0; i < 4; i++) pa[i] = *(float4*)(&KPs[(ty * 4 + i) * RS + k4 * 4]);
      #pragma unroll
      for (int k = 0; k < 4; k++) va[k] = *(float4*)(&Vs[(k4 * 4 + k) * 64 + tx * 4]);
      #pragma unroll
      for (int i = 0; i < 4; i++) {
        float pk[4] = {pa[i].x, pa[i].y, pa[i].z, pa[i].w};
        #pragma unroll
        for (int k = 0; k < 4; k++) {
          acc[i][0] += pk[k] * va[k].x;
          acc[i][1] += pk[k] * va[k].y;
          acc[i][2] += pk[k] * va[k].z;
          acc[i][3] += pk[k] * va[k].w;
        }
      }
    }
  }

  // Epilogue: normalize and write to [B,S,H*D]
  float* ob = Aout + ((size_t)(bb * 512 + qt * 64)) * 2048 + h * 64;
  #pragma unroll
  for (int i = 0; i < 4; i++) {
    int r = ty * 4 + i;
    float inv = 1.0f / rowsum[r];
    float4 o = make_float4(acc[i][0] * inv, acc[i][1] * inv,
                           acc[i][2] * inv, acc[i][3] * inv);
    *(float4*)(&ob[(size_t)r * 2048 + tx * 4]) = o;
  }
}

// ---------------------------------------------------------------------------
extern "C" void kernel_launch(void* const* d_in, const int* in_sizes, int n_in,
                              void* d_out, int out_size, void* d_ws, size_t ws_size,
                              hipStream_t stream)
{
  const float* x  = (const float*)d_in[0];
  const float* Wq = (const float*)d_in[1];
  const float* Wk = (const float*)d_in[2];
  const float* Wv = (const float*)d_in[3];
  const float* Wo = (const float*)d_in[4];

  float* out  = (float*)d_out;                 // [B,S,2048]       8,388,608
  float* kout = out + 8388608;                 // k cache [B,8,S,64] 2,097,152
  float* vout = out + 10485760;                // v cache [B,8,S,64] 2,097,152

  float* ws  = (float*)d_ws;
  float* Qws = ws;                             // [4096,2048] 33.5 MB
  float* Kws = ws + 8388608;                   // [4096,512]   8.4 MB
  float* Aws = ws + 10485760;                  // [4096,2048] 33.5 MB

  gemm_qkv<<<dim3(24, 32), 256, 0, stream>>>(x, Wq, Wk, Wv, Qws, Kws, vout);
  rope_q<<<16384, 256, 0, stream>>>(Qws);
  rope_k<<<4096, 256, 0, stream>>>(Kws, kout);
  attn<<<dim3(8, 32, 8), 256, 0, stream>>>(Qws, kout, vout, Aws);
  gemm_out<<<dim3(16, 32), 256, 0, stream>>>(Aws, Wo, out);
}

// Round 2
// 691.752 us; speedup vs baseline: 2.4181x; 2.4181x over previous
//
#include <hip/hip_runtime.h>
#include <math.h>

// Problem constants
#define BATCH   8
#define SEQ     512
#define HID     2048
#define NH      32
#define NKV     8
#define HD      64
#define SCALE   0.125f          // 1/sqrt(64)

typedef unsigned short u16;
typedef __attribute__((ext_vector_type(8))) short  s16x8;
typedef __attribute__((ext_vector_type(4))) float  f32x4;

// ---- bf16 helpers (RNE, bit-level; no header dependency) -------------------
__device__ __forceinline__ u16 f2bf(float f) {
  unsigned u = __builtin_bit_cast(unsigned, f);
  u += 0x7fffu + ((u >> 16) & 1u);
  return (u16)(u >> 16);
}
__device__ __forceinline__ float bf2f(u16 h) {
  unsigned u = ((unsigned)h) << 16;
  return __builtin_bit_cast(float, u);
}
__device__ __forceinline__ void split_bf16(float v, u16& h, u16& l) {
  h = f2bf(v);
  l = f2bf(v - bf2f(h));
}

// async global->LDS, 16B per lane (guide §5; size must be literal)
#define GL16(gp, lp) __builtin_amdgcn_global_load_lds(                         \
    (const __attribute__((address_space(1))) void*)(gp),                       \
    (__attribute__((address_space(3))) void*)(lp), 16, 0, 0)

// ---------------------------------------------------------------------------
// Pre-pass: fp32 -> bf16 hi/lo planes (elementwise). One float4 per thread.
// ---------------------------------------------------------------------------
__global__ __launch_bounds__(256) void split_x(const float* __restrict__ src,
                                               u16* __restrict__ h,
                                               u16* __restrict__ l)
{
  int i = blockIdx.x * 256 + threadIdx.x;
  float4 v = ((const float4*)src)[i];
  ushort4 hh, ll;
  split_bf16(v.x, hh.x, ll.x);
  split_bf16(v.y, hh.y, ll.y);
  split_bf16(v.z, hh.z, ll.z);
  split_bf16(v.w, hh.w, ll.w);
  ((ushort4*)h)[i] = hh;
  ((ushort4*)l)[i] = ll;
}

// ---------------------------------------------------------------------------
// Pre-pass: transpose + split. W [2048 x N] fp32 row-major ->
// BT planes [nofs+n][k] bf16, leading dim 2048 (K-contiguous for MFMA B).
// 64x64 tiles, LDS transpose (stride 68 keeps float4 reads 16B-aligned).
// ---------------------------------------------------------------------------
__global__ __launch_bounds__(256) void tsplit_w(const float* __restrict__ W, int N,
                                                u16* __restrict__ BTh,
                                                u16* __restrict__ BTl, int nofs)
{
  __shared__ float t[64][68];
  const int nt = blockIdx.x * 64, kt = blockIdx.y * 64;
  const int tid = threadIdx.x;
  const int c4 = (tid & 15) * 4, r0 = tid >> 4;
  #pragma unroll
  for (int i = 0; i < 4; i++) {
    int r = r0 + i * 16;
    float4 v = *(const float4*)(&W[(size_t)(kt + r) * N + nt + c4]);
    t[c4 + 0][r] = v.x; t[c4 + 1][r] = v.y; t[c4 + 2][r] = v.z; t[c4 + 3][r] = v.w;
  }
  __syncthreads();
  #pragma unroll
  for (int i = 0; i < 4; i++) {
    int rr = r0 + i * 16;
    float4 v = *(const float4*)(&t[rr][c4]);
    ushort4 hh, ll;
    split_bf16(v.x, hh.x, ll.x);
    split_bf16(v.y, hh.y, ll.y);
    split_bf16(v.z, hh.z, ll.z);
    split_bf16(v.w, hh.w, ll.w);
    size_t o = (size_t)(nofs + nt + rr) * 2048 + kt + c4;
    *(ushort4*)(&BTh[o]) = hh;
    *(ushort4*)(&BTl[o]) = ll;
  }
}

// ---------------------------------------------------------------------------
// Split-bf16 MFMA GEMM main loop (m97-style 128x128 tile, BK=32, 4 waves).
// A planes [M][2048] bf16 row-major; B planes [N][2048] bf16 row-major (=W^T).
// C = Ah*Bh + Ah*Bl + Al*Bh accumulated fp32 in MFMA.
// Wave w owns 64x64 quadrant (wr,wc); 4x4 fragments of 16x16, K-step 32.
// Fragment layout (guide §3, m89/m91 verified): A/B lane&15 = row/col,
// (lane>>4)*8 = k-offset (8 contiguous bf16 = 1 ds_read_b128);
// C/D: col = lane&15, row = (lane>>4)*4 + reg.
// ---------------------------------------------------------------------------
__device__ __forceinline__ void gemm_main(
    const u16* __restrict__ Ah, const u16* __restrict__ Al,
    const u16* __restrict__ Bh, const u16* __restrict__ Bl,
    int mtile, int ntile,
    u16* sAh, u16* sAl, u16* sBh, u16* sBl,
    f32x4 acc[4][4])
{
  const int tid  = threadIdx.x;
  const int lane = tid & 63;
  const int w    = tid >> 6;
  const int wr = (w >> 1) * 64, wc = (w & 1) * 64;
  const int fr = lane & 15, fk = (lane >> 4) * 8;

  // staging: 512 slots of 16B per plane; thread t handles slots t and t+256.
  // slot s -> row s>>2, col8 (s&3)*8; LDS linear offset = s*8 elements.
  const int r0 = tid >> 2, c0 = (tid & 3) * 8;
  const size_t a0 = (size_t)(mtile + r0) * 2048 + c0;
  const size_t a1 = (size_t)(mtile + r0 + 64) * 2048 + c0;
  const size_t b0 = (size_t)(ntile + r0) * 2048 + c0;
  const size_t b1 = (size_t)(ntile + r0 + 64) * 2048 + c0;
  const int d0 = tid * 8, d1 = tid * 8 + 2048;

  for (int kt = 0; kt < 2048; kt += 32) {
    GL16(Ah + a0 + kt, sAh + d0);
    GL16(Ah + a1 + kt, sAh + d1);
    GL16(Al + a0 + kt, sAl + d0);
    GL16(Al + a1 + kt, sAl + d1);
    GL16(Bh + b0 + kt, sBh + d0);
    GL16(Bh + b1 + kt, sBh + d1);
    GL16(Bl + b0 + kt, sBl + d0);
    GL16(Bl + b1 + kt, sBl + d1);
    __syncthreads();

    s16x8 bhf[4], blf[4];
    #pragma unroll
    for (int ni = 0; ni < 4; ni++) {
      bhf[ni] = *(const s16x8*)(&sBh[(wc + ni * 16 + fr) * 32 + fk]);
      blf[ni] = *(const s16x8*)(&sBl[(wc + ni * 16 + fr) * 32 + fk]);
    }
    #pragma unroll
    for (int mi = 0; mi < 4; mi++) {
      s16x8 ah = *(const s16x8*)(&sAh[(wr + mi * 16 + fr) * 32 + fk]);
      s16x8 al = *(const s16x8*)(&sAl[(wr + mi * 16 + fr) * 32 + fk]);
      #pragma unroll
      for (int ni = 0; ni < 4; ni++) {
        f32x4 c = acc[mi][ni];
        c = __builtin_amdgcn_mfma_f32_16x16x32_bf16(ah, bhf[ni], c, 0, 0, 0);
        c = __builtin_amdgcn_mfma_f32_16x16x32_bf16(ah, blf[ni], c, 0, 0, 0);
        c = __builtin_amdgcn_mfma_f32_16x16x32_bf16(al, bhf[ni], c, 0, 0, 0);
        acc[mi][ni] = c;
      }
    }
    __syncthreads();
  }
}

// Fused QKV projection: N-tiles [0,2048) -> Q ws, [2048,2560) -> K cache,
// [2560,3072) -> V cache (both caches in [B,HKV,S,D] layout, pre-RoPE for K).
__global__ __launch_bounds__(256, 2) void gemm_qkv(
    const u16* __restrict__ Ah, const u16* __restrict__ Al,
    const u16* __restrict__ Bh, const u16* __restrict__ Bl,
    float* __restrict__ Qws, float* __restrict__ kout, float* __restrict__ vout)
{
  __shared__ __align__(16) u16 sAh[128 * 32], sAl[128 * 32], sBh[128 * 32], sBl[128 * 32];
  const int ntile = blockIdx.x * 128, mtile = blockIdx.y * 128;
  f32x4 acc[4][4] = {};
  gemm_main(Ah, Al, Bh, Bl, mtile, ntile, sAh, sAl, sBh, sBl, acc);

  const int lane = threadIdx.x & 63, w = threadIdx.x >> 6;
  const int wr = (w >> 1) * 64, wc = (w & 1) * 64;
  const int orow = (lane >> 4) * 4, ocol = lane & 15;
  #pragma unroll
  for (int mi = 0; mi < 4; mi++)
    #pragma unroll
    for (int r = 0; r < 4; r++) {
      int m = mtile + wr + mi * 16 + orow + r;
      int bb = m >> 9, s = m & 511;
      #pragma unroll
      for (int ni = 0; ni < 4; ni++) {
        int n = ntile + wc + ni * 16 + ocol;
        float v = acc[mi][ni][r];
        if (ntile < 2048) {
          Qws[(size_t)m * 2048 + n] = v;
        } else if (ntile < 2560) {
          int np = n - 2048, hk = np >> 6, d = np & 63;
          kout[((size_t)(bb * 8 + hk) * 512 + s) * 64 + d] = v;
        } else {
          int np = n - 2560, hk = np >> 6, d = np & 63;
          vout[((size_t)(bb * 8 + hk) * 512 + s) * 64 + d] = v;
        }
      }
    }
}

// Output projection: out = Ao[4096,2048] @ Wo (via WoT planes)
__global__ __launch_bounds__(256, 2) void gemm_out(
    const u16* __restrict__ Ah, const u16* __restrict__ Al,
    const u16* __restrict__ Bh, const u16* __restrict__ Bl,
    float* __restrict__ Cout)
{
  __shared__ __align__(16) u16 sAh[128 * 32], sAl[128 * 32], sBh[128 * 32], sBl[128 * 32];
  const int ntile = blockIdx.x * 128, mtile = blockIdx.y * 128;
  f32x4 acc[4][4] = {};
  gemm_main(Ah, Al, Bh, Bl, mtile, ntile, sAh, sAl, sBh, sBl, acc);

  const int lane = threadIdx.x & 63, w = threadIdx.x >> 6;
  const int wr = (w >> 1) * 64, wc = (w & 1) * 64;
  const int orow = (lane >> 4) * 4, ocol = lane & 15;
  #pragma unroll
  for (int mi = 0; mi < 4; mi++)
    #pragma unroll
    for (int r = 0; r < 4; r++) {
      int m = mtile + wr + mi * 16 + orow + r;
      #pragma unroll
      for (int ni = 0; ni < 4; ni++) {
        int n = ntile + wc + ni * 16 + ocol;
        Cout[(size_t)m * 2048 + n] = acc[mi][ni][r];
      }
    }
}

// ---------------------------------------------------------------------------
// RoPE on Q, in place in [B,S,H*D] layout. One thread per (d, d+32) pair.
__global__ void rope_q(float* __restrict__ Q)
{
  int idx = blockIdx.x * 256 + threadIdx.x;
  int m = idx >> 10; int r = idx & 1023;
  int h = r >> 5;    int i = r & 31;
  int s = m & 511;
  float inv = powf(10000.0f, -(float)i * (1.0f / 32.0f));
  float th = (float)s * inv;
  float sn, cs; sincosf(th, &sn, &cs);
  float* p = Q + (size_t)m * 2048 + h * 64 + i;
  float q0 = p[0], q1 = p[32];
  p[0]  = q0 * cs - q1 * sn;
  p[32] = q1 * cs + q0 * sn;
}

// RoPE on K, in place in the k-cache [B*HKV, S, D].
__global__ void rope_k(float* __restrict__ kc)
{
  int idx = blockIdx.x * 256 + threadIdx.x;   // B*HKV*S*32 = 1,048,576
  int i = idx & 31;
  int s = (idx >> 5) & 511;
  int bh = idx >> 14;
  float inv = powf(10000.0f, -(float)i * (1.0f / 32.0f));
  float th = (float)s * inv;
  float sn, cs; sincosf(th, &sn, &cs);
  float* p = kc + ((size_t)bh * 512 + s) * 64 + i;
  float k0 = p[0], k1 = p[32];
  p[0]  = k0 * cs - k1 * sn;
  p[32] = k1 * cs + k0 * sn;
}

// ---------------------------------------------------------------------------
// Flash-style causal GQA attention, fp32 (unchanged from R1 except epilogue
// now emits bf16 hi/lo planes for the split-MFMA output projection).
// ---------------------------------------------------------------------------
#define RS 68

__global__ __launch_bounds__(256, 2)
void attn(const float* __restrict__ Qws, const float* __restrict__ kc,
          const float* __restrict__ vc,
          u16* __restrict__ AoH, u16* __restrict__ AoL)
{
  __shared__ float Qs[64 * RS];
  __shared__ float KPs[64 * RS];   // K tile, then reused as P tile
  __shared__ float Vs[64 * 64];
  __shared__ float rowscale[64], rowsum[64];

  const int qt = blockIdx.x, h = blockIdx.y, bb = blockIdx.z;
  const int hk = h >> 2;
  const int tid = threadIdx.x;
  const int tx = tid & 15, ty = tid >> 4;
  const int sr = tid >> 2, sg = tid & 3;

  const float* qbase = Qws + ((size_t)(bb * 512 + qt * 64)) * 2048 + h * 64;
  #pragma unroll
  for (int i0 = 0; i0 < 4; i0++) {
    int e = tid + 256 * i0;
    int r = e >> 4, d4 = (e & 15) * 4;
    *(float4*)(&Qs[r * RS + d4]) = *(const float4*)(&qbase[(size_t)r * 2048 + d4]);
  }

  float acc[4][4] = {};
  float m_r = -1e30f, l_r = 0.0f;
  const size_t kvbase = ((size_t)(bb * 8 + hk)) * 512 * 64;

  for (int j = 0; j <= qt; j++) {
    __syncthreads();
    const float* kb = kc + kvbase + (size_t)j * 64 * 64;
    const float* vb = vc + kvbase + (size_t)j * 64 * 64;
    #pragma unroll
    for (int i0 = 0; i0 < 4; i0++) {
      int e = tid + 256 * i0;
      int r = e >> 4, d4 = (e & 15) * 4;
      *(float4*)(&KPs[r * RS + d4]) = *(const float4*)(&kb[r * 64 + d4]);
      *(float4*)(&Vs[r * 64 + d4])  = *(const float4*)(&vb[r * 64 + d4]);
    }
    __syncthreads();

    float sacc[4][4] = {};
    #pragma unroll
    for (int k4 = 0; k4 < 16; k4++) {
      float4 qa[4], ka[4];
      #pragma unroll
      for (int i = 0; i < 4; i++) qa[i] = *(float4*)(&Qs[(ty * 4 + i) * RS + k4 * 4]);
      #pragma unroll
      for (int c = 0; c < 4; c++) ka[c] = *(float4*)(&KPs[(tx + 16 * c) * RS + k4 * 4]);
      #pragma unroll
      for (int i = 0; i < 4; i++)
        #pragma unroll
        for (int c = 0; c < 4; c++)
          sacc[i][c] += qa[i].x * ka[c].x + qa[i].y * ka[c].y +
                        qa[i].z * ka[c].z + qa[i].w * ka[c].w;
    }
    __syncthreads();

    #pragma unroll
    for (int i = 0; i < 4; i++) {
      int qg = qt * 64 + ty * 4 + i;
      #pragma unroll
      for (int c = 0; c < 4; c++) {
        int kg = j * 64 + tx + 16 * c;
        float sv = sacc[i][c] * SCALE;
        if (kg > qg) sv = -1e30f;
        KPs[(ty * 4 + i) * RS + tx + 16 * c] = sv;
      }
    }
    __syncthreads();

    float4 pv[4];
    float tm = -1e30f;
    #pragma unroll
    for (int c4 = 0; c4 < 4; c4++) {
      pv[c4] = *(float4*)(&KPs[sr * RS + sg * 16 + c4 * 4]);
      tm = fmaxf(tm, fmaxf(fmaxf(pv[c4].x, pv[c4].y), fmaxf(pv[c4].z, pv[c4].w)));
    }
    tm = fmaxf(tm, __shfl_xor(tm, 1));
    tm = fmaxf(tm, __shfl_xor(tm, 2));
    float mnew = fmaxf(m_r, tm);
    float sc_old = __expf(m_r - mnew);
    float lsum = 0.0f;
    #pragma unroll
    for (int c4 = 0; c4 < 4; c4++) {
      pv[c4].x = __expf(pv[c4].x - mnew);
      pv[c4].y = __expf(pv[c4].y - mnew);
      pv[c4].z = __expf(pv[c4].z - mnew);
      pv[c4].w = __expf(pv[c4].w - mnew);
      lsum += pv[c4].x + pv[c4].y + pv[c4].z + pv[c4].w;
      *(float4*)(&KPs[sr * RS + sg * 16 + c4 * 4]) = pv[c4];
    }
    lsum += __shfl_xor(lsum, 1);
    lsum += __shfl_xor(lsum, 2);
    l_r = l_r * sc_old + lsum;
    m_r = mnew;
    if (sg == 0) { rowscale[sr] = sc_old; rowsum[sr] = l_r; }
    __syncthreads();

    #pragma unroll
    for (int i = 0; i < 4; i++) {
      float rsc = rowscale[ty * 4 + i];
      #pragma unroll
      for (int jj = 0; jj < 4; jj++) acc[i][jj] *= rsc;
    }
    #pragma unroll
    for (int k4 = 0; k4 < 16; k4++) {
      float4 pa[4], va[4];
      #pragma unroll
      for (int i = 0; i < 4; i++) pa[i] = *(float4*)(&KPs[(ty * 4 + i) * RS + k4 * 4]);
      #pragma unroll
      for (int k = 0; k < 4; k++) va[k] = *(float4*)(&Vs[(k4 * 4 + k) * 64 + tx * 4]);
      #pragma unroll
      for (int i = 0; i < 4; i++) {
        float pk[4] = {pa[i].x, pa[i].y, pa[i].z, pa[i].w};
        #pragma unroll
        for (int k = 0; k < 4; k++) {
          acc[i][0] += pk[k] * va[k].x;
          acc[i][1] += pk[k] * va[k].y;
          acc[i][2] += pk[k] * va[k].z;
          acc[i][3] += pk[k] * va[k].w;
        }
      }
    }
  }

  // Epilogue: normalize and emit bf16 hi/lo planes [B,S,H*D]
  size_t obase = ((size_t)(bb * 512 + qt * 64)) * 2048 + h * 64;
  #pragma unroll
  for (int i = 0; i < 4; i++) {
    int r = ty * 4 + i;
    float inv = 1.0f / rowsum[r];
    ushort4 hh, ll;
    split_bf16(acc[i][0] * inv, hh.x, ll.x);
    split_bf16(acc[i][1] * inv, hh.y, ll.y);
    split_bf16(acc[i][2] * inv, hh.z, ll.z);
    split_bf16(acc[i][3] * inv, hh.w, ll.w);
    *(ushort4*)(&AoH[obase + (size_t)r * 2048 + tx * 4]) = hh;
    *(ushort4*)(&AoL[obase + (size_t)r * 2048 + tx * 4]) = ll;
  }
}

// ---------------------------------------------------------------------------
extern "C" void kernel_launch(void* const* d_in, const int* in_sizes, int n_in,
                              void* d_out, int out_size, void* d_ws, size_t ws_size,
                              hipStream_t stream)
{
  const float* x  = (const float*)d_in[0];
  const float* Wq = (const float*)d_in[1];
  const float* Wk = (const float*)d_in[2];
  const float* Wv = (const float*)d_in[3];
  const float* Wo = (const float*)d_in[4];

  float* out  = (float*)d_out;                 // [B,S,2048]
  float* kout = out + 8388608;                 // k cache [B,8,S,64]
  float* vout = out + 10485760;                // v cache [B,8,S,64]

  // Workspace layout (92.3 MB total):
  //   [0, 32M)   : Qws fp32 [4096,2048]
  //   [32M, 64M) : phase1 xh/xl planes; phase2 AoH/AoL planes (aliased)
  //   [64M, 88M) : phase1 WqkvT planes [3072,2048]x2; phase2 WoT planes (aliased)
  uint8_t* wsb = (uint8_t*)d_ws;
  float* Qws = (float*)wsb;
  u16* xh  = (u16*)(wsb + 33554432);
  u16* xl  = (u16*)(wsb + 50331648);
  u16* AoH = xh;                               // alias: x planes dead after gemm_qkv
  u16* AoL = xl;
  u16* Wqh = (u16*)(wsb + 67108864);
  u16* Wql = (u16*)(wsb + 79691776);
  u16* Woh = (u16*)(wsb + 67108864);           // alias: Wqkv planes dead after gemm_qkv
  u16* Wol = (u16*)(wsb + 75497472);

  split_x<<<8192, 256, 0, stream>>>(x, xh, xl);
  tsplit_w<<<dim3(32, 32), 256, 0, stream>>>(Wq, 2048, Wqh, Wql, 0);
  tsplit_w<<<dim3(8, 32), 256, 0, stream>>>(Wk, 512, Wqh, Wql, 2048);
  tsplit_w<<<dim3(8, 32), 256, 0, stream>>>(Wv, 512, Wqh, Wql, 2560);
  gemm_qkv<<<dim3(24, 32), 256, 0, stream>>>(xh, xl, Wqh, Wql, Qws, kout, vout);
  rope_q<<<16384, 256, 0, stream>>>(Qws);
  rope_k<<<4096, 256, 0, stream>>>(kout);
  tsplit_w<<<dim3(32, 32), 256, 0, stream>>>(Wo, 2048, Woh, Wol, 0);
  attn<<<dim3(8, 32, 8), 256, 0, stream>>>(Qws, kout, vout, AoH, AoL);
  gemm_out<<<dim3(16, 32), 256, 0, stream>>>(AoH, AoL, Woh, Wol, out);
}

// Round 4
// 459.736 us; speedup vs baseline: 3.6384x; 1.5047x over previous
//
#include <hip/hip_runtime.h>
#include <math.h>

// Problem constants
#define BATCH   8
#define SEQ     512
#define HID     2048
#define NH      32
#define NKV     8
#define HD      64

typedef unsigned short u16;
typedef __attribute__((ext_vector_type(8))) short  s16x8;
typedef __attribute__((ext_vector_type(4))) float  f32x4;

// ---- bf16 helpers (RNE, bit-level) ----------------------------------------
__device__ __forceinline__ u16 f2bf(float f) {
  unsigned u = __builtin_bit_cast(unsigned, f);
  u += 0x7fffu + ((u >> 16) & 1u);
  return (u16)(u >> 16);
}
__device__ __forceinline__ float bf2f(u16 h) {
  unsigned u = ((unsigned)h) << 16;
  return __builtin_bit_cast(float, u);
}
__device__ __forceinline__ void split_bf16(float v, u16& h, u16& l) {
  h = f2bf(v);
  l = f2bf(v - bf2f(h));
}

// async global->LDS, 16B per lane
#define GL16(gp, lp) __builtin_amdgcn_global_load_lds(                         \
    (const __attribute__((address_space(1))) void*)(gp),                       \
    (__attribute__((address_space(3))) void*)(lp), 16, 0, 0)

#define MFMA16(a, b, c) __builtin_amdgcn_mfma_f32_16x16x32_bf16((a), (b), (c), 0, 0, 0)

// ---------------------------------------------------------------------------
// Pre-pass: fp32 -> bf16 hi/lo planes (elementwise).
// ---------------------------------------------------------------------------
__global__ __launch_bounds__(256) void split_x(const float* __restrict__ src,
                                               u16* __restrict__ h,
                                               u16* __restrict__ l)
{
  int i = blockIdx.x * 256 + threadIdx.x;
  float4 v = ((const float4*)src)[i];
  ushort4 hh, ll;
  split_bf16(v.x, hh.x, ll.x);
  split_bf16(v.y, hh.y, ll.y);
  split_bf16(v.z, hh.z, ll.z);
  split_bf16(v.w, hh.w, ll.w);
  ((ushort4*)h)[i] = hh;
  ((ushort4*)l)[i] = ll;
}

// ---------------------------------------------------------------------------
// Pre-pass: transpose + split W [2048 x N] -> BT planes [nofs+n][2048] bf16.
// ---------------------------------------------------------------------------
__global__ __launch_bounds__(256) void tsplit_w(const float* __restrict__ W, int N,
                                                u16* __restrict__ BTh,
                                                u16* __restrict__ BTl, int nofs)
{
  __shared__ float t[64][68];
  const int nt = blockIdx.x * 64, kt = blockIdx.y * 64;
  const int tid = threadIdx.x;
  const int c4 = (tid & 15) * 4, r0 = tid >> 4;
  #pragma unroll
  for (int i = 0; i < 4; i++) {
    int r = r0 + i * 16;
    float4 v = *(const float4*)(&W[(size_t)(kt + r) * N + nt + c4]);
    t[c4 + 0][r] = v.x; t[c4 + 1][r] = v.y; t[c4 + 2][r] = v.z; t[c4 + 3][r] = v.w;
  }
  __syncthreads();
  #pragma unroll
  for (int i = 0; i < 4; i++) {
    int rr = r0 + i * 16;
    float4 v = *(const float4*)(&t[rr][c4]);
    ushort4 hh, ll;
    split_bf16(v.x, hh.x, ll.x);
    split_bf16(v.y, hh.y, ll.y);
    split_bf16(v.z, hh.z, ll.z);
    split_bf16(v.w, hh.w, ll.w);
    size_t o = (size_t)(nofs + nt + rr) * 2048 + kt + c4;
    *(ushort4*)(&BTh[o]) = hh;
    *(ushort4*)(&BTl[o]) = ll;
  }
}

// ---------------------------------------------------------------------------
// Split-bf16 MFMA GEMM main loop (128x128 tile, BK=32, 4 waves).
// ---------------------------------------------------------------------------
__device__ __forceinline__ void gemm_main(
    const u16* __restrict__ Ah, const u16* __restrict__ Al,
    const u16* __restrict__ Bh, const u16* __restrict__ Bl,
    int mtile, int ntile,
    u16* sAh, u16* sAl, u16* sBh, u16* sBl,
    f32x4 acc[4][4])
{
  const int tid  = threadIdx.x;
  const int lane = tid & 63;
  const int w    = tid >> 6;
  const int wr = (w >> 1) * 64, wc = (w & 1) * 64;
  const int fr = lane & 15, fk = (lane >> 4) * 8;

  const int r0 = tid >> 2, c0 = (tid & 3) * 8;
  const size_t a0 = (size_t)(mtile + r0) * 2048 + c0;
  const size_t a1 = (size_t)(mtile + r0 + 64) * 2048 + c0;
  const size_t b0 = (size_t)(ntile + r0) * 2048 + c0;
  const size_t b1 = (size_t)(ntile + r0 + 64) * 2048 + c0;
  const int d0 = tid * 8, d1 = tid * 8 + 2048;

  for (int kt = 0; kt < 2048; kt += 32) {
    GL16(Ah + a0 + kt, sAh + d0);
    GL16(Ah + a1 + kt, sAh + d1);
    GL16(Al + a0 + kt, sAl + d0);
    GL16(Al + a1 + kt, sAl + d1);
    GL16(Bh + b0 + kt, sBh + d0);
    GL16(Bh + b1 + kt, sBh + d1);
    GL16(Bl + b0 + kt, sBl + d0);
    GL16(Bl + b1 + kt, sBl + d1);
    __syncthreads();

    s16x8 bhf[4], blf[4];
    #pragma unroll
    for (int ni = 0; ni < 4; ni++) {
      bhf[ni] = *(const s16x8*)(&sBh[(wc + ni * 16 + fr) * 32 + fk]);
      blf[ni] = *(const s16x8*)(&sBl[(wc + ni * 16 + fr) * 32 + fk]);
    }
    #pragma unroll
    for (int mi = 0; mi < 4; mi++) {
      s16x8 ah = *(const s16x8*)(&sAh[(wr + mi * 16 + fr) * 32 + fk]);
      s16x8 al = *(const s16x8*)(&sAl[(wr + mi * 16 + fr) * 32 + fk]);
      #pragma unroll
      for (int ni = 0; ni < 4; ni++) {
        f32x4 c = acc[mi][ni];
        c = MFMA16(ah, bhf[ni], c);
        c = MFMA16(ah, blf[ni], c);
        c = MFMA16(al, bhf[ni], c);
        acc[mi][ni] = c;
      }
    }
    __syncthreads();
  }
}

// ---------------------------------------------------------------------------
// Fused QKV projection + in-register RoPE + bf16 plane emission.
// N-tiles [0,2048): Q -> roped+scaled bf16 hi/lo planes [m][2048]
// N-tiles [2048,2560): K -> roped fp32 k-cache + bf16 hi/lo planes [bh][s][d]
// N-tiles [2560,3072): V -> fp32 v-cache + bf16 transposed plane [bh][d][s]
// Each wave's 64-col window aligns with one head, so the (d, d+32) RoPE pair
// is lane-resident: acc[mi][nj] pairs with acc[mi][nj+2].
// ---------------------------------------------------------------------------
#define L2_10K 13.28771238f   // log2(10000)

__global__ __launch_bounds__(256, 2) void gemm_qkv(
    const u16* __restrict__ Ah, const u16* __restrict__ Al,
    const u16* __restrict__ Bh, const u16* __restrict__ Bl,
    u16* __restrict__ Qh, u16* __restrict__ Ql,
    float* __restrict__ kout, float* __restrict__ vout,
    u16* __restrict__ Kh, u16* __restrict__ Kl, u16* __restrict__ Vt)
{
  __shared__ __align__(16) u16 sAh[128 * 32], sAl[128 * 32], sBh[128 * 32], sBl[128 * 32];
  const int ntile = blockIdx.x * 128, mtile = blockIdx.y * 128;
  f32x4 acc[4][4] = {};
  gemm_main(Ah, Al, Bh, Bl, mtile, ntile, sAh, sAl, sBh, sBl, acc);

  const int lane = threadIdx.x & 63, w = threadIdx.x >> 6;
  const int wr = (w >> 1) * 64, wc = (w & 1) * 64;
  const int orow = (lane >> 4) * 4, ocol = lane & 15;

  if (ntile < 2048) {
    // rotation index i = nj*16 + ocol (nj in {0,1}); inv freq per nj
    float inv[2];
    #pragma unroll
    for (int nj = 0; nj < 2; nj++)
      inv[nj] = exp2f((float)(nj * 16 + ocol) * (-L2_10K / 32.0f));
    #pragma unroll
    for (int mi = 0; mi < 4; mi++)
      #pragma unroll
      for (int r = 0; r < 4; r++) {
        int m = mtile + wr + mi * 16 + orow + r;
        int s = m & 511;
        #pragma unroll
        for (int nj = 0; nj < 2; nj++) {
          float th = (float)s * inv[nj];
          float sn, cs; sincosf(th, &sn, &cs);
          float a0 = acc[mi][nj][r]     * 0.125f;   // scale folded into Q
          float a1 = acc[mi][nj + 2][r] * 0.125f;
          float q0 = a0 * cs - a1 * sn;
          float q1 = a1 * cs + a0 * sn;
          size_t o0 = (size_t)m * 2048 + ntile + wc + nj * 16 + ocol;
          u16 hh, ll;
          split_bf16(q0, hh, ll); Qh[o0] = hh;      Ql[o0] = ll;
          split_bf16(q1, hh, ll); Qh[o0 + 32] = hh; Ql[o0 + 32] = ll;
        }
      }
  } else if (ntile < 2560) {
    float inv[2];
    #pragma unroll
    for (int nj = 0; nj < 2; nj++)
      inv[nj] = exp2f((float)(nj * 16 + ocol) * (-L2_10K / 32.0f));
    #pragma unroll
    for (int mi = 0; mi < 4; mi++)
      #pragma unroll
      for (int r = 0; r < 4; r++) {
        int m = mtile + wr + mi * 16 + orow + r;
        int bb = m >> 9, s = m & 511;
        #pragma unroll
        for (int nj = 0; nj < 2; nj++) {
          int np = ntile + wc + nj * 16 + ocol - 2048;
          int hk = np >> 6, d = np & 63;            // d in [0,32)
          float th = (float)s * inv[nj];
          float sn, cs; sincosf(th, &sn, &cs);
          float a0 = acc[mi][nj][r];
          float a1 = acc[mi][nj + 2][r];
          float k0 = a0 * cs - a1 * sn;
          float k1 = a1 * cs + a0 * sn;
          size_t o = ((size_t)(bb * 8 + hk) * 512 + s) * 64 + d;
          kout[o] = k0; kout[o + 32] = k1;
          u16 hh, ll;
          split_bf16(k0, hh, ll); Kh[o] = hh;      Kl[o] = ll;
          split_bf16(k1, hh, ll); Kh[o + 32] = hh; Kl[o + 32] = ll;
        }
      }
  } else {
    #pragma unroll
    for (int mi = 0; mi < 4; mi++)
      #pragma unroll
      for (int ni = 0; ni < 4; ni++) {
        int np = ntile + wc + ni * 16 + ocol - 2560;
        int hk = np >> 6, d = np & 63;
        int m0 = mtile + wr + mi * 16 + orow;
        int bb = m0 >> 9, s0 = m0 & 511;            // multiple of 4
        ushort4 pk;
        #pragma unroll
        for (int r = 0; r < 4; r++) {
          float v = acc[mi][ni][r];
          vout[((size_t)(bb * 8 + hk) * 512 + s0 + r) * 64 + d] = v;
          ((u16*)&pk)[r] = f2bf(v);
        }
        *(ushort4*)(&Vt[((size_t)(bb * 8 + hk) * 64 + d) * 512 + s0]) = pk;
      }
  }
}

// ---------------------------------------------------------------------------
// Output projection: out = Ao[4096,2048] @ Wo (split planes)
// ---------------------------------------------------------------------------
__global__ __launch_bounds__(256, 2) void gemm_out(
    const u16* __restrict__ Ah, const u16* __restrict__ Al,
    const u16* __restrict__ Bh, const u16* __restrict__ Bl,
    float* __restrict__ Cout)
{
  __shared__ __align__(16) u16 sAh[128 * 32], sAl[128 * 32], sBh[128 * 32], sBl[128 * 32];
  const int ntile = blockIdx.x * 128, mtile = blockIdx.y * 128;
  f32x4 acc[4][4] = {};
  gemm_main(Ah, Al, Bh, Bl, mtile, ntile, sAh, sAl, sBh, sBl, acc);

  const int lane = threadIdx.x & 63, w = threadIdx.x >> 6;
  const int wr = (w >> 1) * 64, wc = (w & 1) * 64;
  const int orow = (lane >> 4) * 4, ocol = lane & 15;
  #pragma unroll
  for (int mi = 0; mi < 4; mi++)
    #pragma unroll
    for (int r = 0; r < 4; r++) {
      int m = mtile + wr + mi * 16 + orow + r;
      #pragma unroll
      for (int ni = 0; ni < 4; ni++)
        Cout[(size_t)m * 2048 + ntile + wc + ni * 16 + ocol] = acc[mi][ni][r];
    }
}

// ---------------------------------------------------------------------------
// MFMA flash attention. Block = (qt, h, b), 4 waves; wave w owns q-rows
// w*16..w*16+15. QK^T = 3-term split bf16; PV = single bf16 (P in [0,1]).
// All LDS tiles XOR-swizzled (byte ^= (row&7)<<4) both-sides (rule #21):
// staging pre-swizzles the global source column, reads apply the same XOR.
// P strip is per-wave (write->read same wave: no barrier needed).
// ---------------------------------------------------------------------------
__global__ __launch_bounds__(256, 2)
void attn(const u16* __restrict__ Qh, const u16* __restrict__ Ql,
          const u16* __restrict__ Kh, const u16* __restrict__ Kl,
          const u16* __restrict__ Vt,
          u16* __restrict__ AoH, u16* __restrict__ AoL)
{
  __shared__ __align__(16) u16 sKh[4096], sKl[4096], sVt[4096];  // 8 KB each
  __shared__ __align__(16) u16 sP[4][1024];                      // 2 KB/wave

  const int qt = blockIdx.x, h = blockIdx.y, bb = blockIdx.z;
  const int hk = h >> 2, bh = bb * 8 + hk;
  const int tid = threadIdx.x, lane = tid & 63, w = tid >> 6;
  const int fr = lane & 15, fg = lane >> 4;

  // Q fragments, hoisted (rows w*16+fr), K=64 -> 2 ksteps, hi/lo planes
  const int qrow = bb * 512 + qt * 64 + w * 16 + fr;
  const size_t qoff = (size_t)qrow * 2048 + h * 64 + fg * 8;
  const s16x8 qh0 = *(const s16x8*)(Qh + qoff);
  const s16x8 qh1 = *(const s16x8*)(Qh + qoff + 32);
  const s16x8 ql0 = *(const s16x8*)(Ql + qoff);
  const s16x8 ql1 = *(const s16x8*)(Ql + qoff + 32);

  f32x4 oacc[4] = {};
  float m_r[4] = {-1e30f, -1e30f, -1e30f, -1e30f};
  float l_r[4] = {};

  const size_t kbase = (size_t)bh * 512 * 64;   // K planes [bh][s][d]
  const size_t vbase = (size_t)bh * 64 * 512;   // Vt plane [bh][d][s]

  for (int j = 0; j <= qt; j++) {
    __syncthreads();   // prior-iter K/Vt reads complete before restage
    #pragma unroll
    for (int p = 0; p < 2; p++) {
      int s = tid + p * 256;
      int row = s >> 3, c8 = (s & 7) ^ (row & 7);   // pre-swizzled source col
      GL16(Kh + kbase + (size_t)(j * 64 + row) * 64 + c8 * 8, sKh + s * 8);
      GL16(Kl + kbase + (size_t)(j * 64 + row) * 64 + c8 * 8, sKl + s * 8);
      GL16(Vt + vbase + (size_t)row * 512 + j * 64 + c8 * 8,  sVt + s * 8);
    }
    __syncthreads();   // compiler drains vmcnt before barrier

    // ---- S = (Q*scale) K^T, 3-term split ----
    f32x4 sacc[4] = {};
    #pragma unroll
    for (int ni = 0; ni < 4; ni++) {
      #pragma unroll
      for (int ks = 0; ks < 2; ks++) {
        int row = ni * 16 + fr;                      // kv index (B n-dim)
        int byte = row * 128 + ((fg * 16 + ks * 64) ^ ((row & 7) << 4));
        s16x8 kh = *(const s16x8*)((const char*)sKh + byte);
        s16x8 kl = *(const s16x8*)((const char*)sKl + byte);
        s16x8 qa = ks ? qh1 : qh0;
        s16x8 qb = ks ? ql1 : ql0;
        f32x4 c = sacc[ni];
        c = MFMA16(qa, kh, c);
        c = MFMA16(qa, kl, c);
        c = MFMA16(qb, kh, c);
        sacc[ni] = c;
      }
    }

    // ---- causal mask + online softmax (rows = fg*4+r, cols over fr,ni) ----
    const int rowg0 = qt * 64 + w * 16 + fg * 4;
    #pragma unroll
    for (int r = 0; r < 4; r++) {
      float mx = -1e30f;
      #pragma unroll
      for (int ni = 0; ni < 4; ni++) {
        int col = j * 64 + ni * 16 + fr;
        float v = (col <= rowg0 + r) ? sacc[ni][r] : -1e30f;
        sacc[ni][r] = v;
        mx = fmaxf(mx, v);
      }
      mx = fmaxf(mx, __shfl_xor(mx, 1));
      mx = fmaxf(mx, __shfl_xor(mx, 2));
      mx = fmaxf(mx, __shfl_xor(mx, 4));
      mx = fmaxf(mx, __shfl_xor(mx, 8));
      float mnew = fmaxf(m_r[r], mx);
      float sc = __expf(m_r[r] - mnew);
      m_r[r] = mnew;
      float ls = 0.0f;
      #pragma unroll
      for (int ni = 0; ni < 4; ni++) {
        float p = __expf(sacc[ni][r] - mnew);
        sacc[ni][r] = p;
        ls += p;
      }
      ls += __shfl_xor(ls, 1);
      ls += __shfl_xor(ls, 2);
      ls += __shfl_xor(ls, 4);
      ls += __shfl_xor(ls, 8);
      l_r[r] = l_r[r] * sc + ls;
      #pragma unroll
      for (int nd = 0; nd < 4; nd++) oacc[nd][r] *= sc;
    }

    // ---- P -> per-wave LDS strip (bf16, swizzled) ----
    u16* pbuf = sP[w];
    #pragma unroll
    for (int ni = 0; ni < 4; ni++)
      #pragma unroll
      for (int r = 0; r < 4; r++) {
        int prow = fg * 4 + r, pcol = ni * 16 + fr;
        int byte = prow * 128 + ((pcol * 2) ^ ((prow & 7) << 4));
        *(u16*)((char*)pbuf + byte) = f2bf(sacc[ni][r]);
      }

    // ---- O += P V ----
    #pragma unroll
    for (int ks = 0; ks < 2; ks++) {
      int pbyte = fr * 128 + ((fg * 16 + ks * 64) ^ ((fr & 7) << 4));
      s16x8 pa = *(const s16x8*)((const char*)pbuf + pbyte);
      #pragma unroll
      for (int nd = 0; nd < 4; nd++) {
        int vrow = nd * 16 + fr;                    // d (B n-dim)
        int vbyte = vrow * 128 + ((fg * 16 + ks * 64) ^ ((vrow & 7) << 4));
        s16x8 vb = *(const s16x8*)((const char*)sVt + vbyte);
        oacc[nd] = MFMA16(pa, vb, oacc[nd]);
      }
    }
  }

  // ---- epilogue: normalize, emit bf16 hi/lo planes [m][2048] ----
  const size_t obase = (size_t)(bb * 512 + qt * 64 + w * 16 + fg * 4) * 2048 + h * 64;
  #pragma unroll
  for (int r = 0; r < 4; r++) {
    float inv = 1.0f / l_r[r];
    #pragma unroll
    for (int nd = 0; nd < 4; nd++) {
      float v = oacc[nd][r] * inv;
      u16 hh, ll; split_bf16(v, hh, ll);
      size_t o = obase + (size_t)r * 2048 + nd * 16 + fr;
      AoH[o] = hh; AoL[o] = ll;
    }
  }
}

// ---------------------------------------------------------------------------
extern "C" void kernel_launch(void* const* d_in, const int* in_sizes, int n_in,
                              void* d_out, int out_size, void* d_ws, size_t ws_size,
                              hipStream_t stream)
{
  const float* x  = (const float*)d_in[0];
  const float* Wq = (const float*)d_in[1];
  const float* Wk = (const float*)d_in[2];
  const float* Wv = (const float*)d_in[3];
  const float* Wo = (const float*)d_in[4];

  float* out  = (float*)d_out;                 // [B,S,2048]
  float* kout = out + 8388608;                 // k cache [B,8,S,64]
  float* vout = out + 10485760;                // v cache [B,8,S,64]

  // Workspace layout (100 MiB):
  //  [0,16M)      xh   -> AoH (alias)
  //  [16M,32M)    xl   -> AoL (alias)
  //  [32M,56M)    Wqkv planes -> Wo planes (alias)
  //  [56M,88M)    Qh/Ql roped+scaled bf16 planes
  //  [88M,96M)    Kh/Kl roped bf16 planes
  //  [96M,100M)   Vt transposed bf16 plane
  uint8_t* wsb = (uint8_t*)d_ws;
  u16* xh  = (u16*)(wsb + 0);
  u16* xl  = (u16*)(wsb + 16777216);
  u16* AoH = xh;
  u16* AoL = xl;
  u16* Wqh = (u16*)(wsb + 33554432);
  u16* Wql = (u16*)(wsb + 46137344);
  u16* Woh = (u16*)(wsb + 33554432);
  u16* Wol = (u16*)(wsb + 41943040);
  u16* Qhp = (u16*)(wsb + 58720256);
  u16* Qlp = (u16*)(wsb + 75497472);
  u16* Khp = (u16*)(wsb + 92274688);
  u16* Klp = (u16*)(wsb + 96468992);
  u16* Vtp = (u16*)(wsb + 100663296);

  split_x<<<8192, 256, 0, stream>>>(x, xh, xl);
  tsplit_w<<<dim3(32, 32), 256, 0, stream>>>(Wq, 2048, Wqh, Wql, 0);
  tsplit_w<<<dim3(8, 32), 256, 0, stream>>>(Wk, 512, Wqh, Wql, 2048);
  tsplit_w<<<dim3(8, 32), 256, 0, stream>>>(Wv, 512, Wqh, Wql, 2560);
  gemm_qkv<<<dim3(24, 32), 256, 0, stream>>>(xh, xl, Wqh, Wql,
                                             Qhp, Qlp, kout, vout, Khp, Klp, Vtp);
  tsplit_w<<<dim3(32, 32), 256, 0, stream>>>(Wo, 2048, Woh, Wol, 0);
  attn<<<dim3(8, 32, 8), 256, 0, stream>>>(Qhp, Qlp, Khp, Klp, Vtp, AoH, AoL);
  gemm_out<<<dim3(16, 32), 256, 0, stream>>>(AoH, AoL, Woh, Wol, out);
}

// Round 5
// 358.957 us; speedup vs baseline: 4.6599x; 1.2808x over previous
//
#include <hip/hip_runtime.h>
#include <math.h>

// Problem constants
#define BATCH   8
#define SEQ     512
#define HID     2048
#define NH      32
#define NKV     8
#define HD      64

typedef unsigned short u16;
typedef __attribute__((ext_vector_type(8))) short  s16x8;
typedef __attribute__((ext_vector_type(4))) float  f32x4;

// ---- bf16 helpers (RNE, bit-level) ----------------------------------------
__device__ __forceinline__ u16 f2bf(float f) {
  unsigned u = __builtin_bit_cast(unsigned, f);
  u += 0x7fffu + ((u >> 16) & 1u);
  return (u16)(u >> 16);
}
__device__ __forceinline__ float bf2f(u16 h) {
  unsigned u = ((unsigned)h) << 16;
  return __builtin_bit_cast(float, u);
}
__device__ __forceinline__ void split_bf16(float v, u16& h, u16& l) {
  h = f2bf(v);
  l = f2bf(v - bf2f(h));
}

// async global->LDS, 16B per lane
#define GL16(gp, lp) __builtin_amdgcn_global_load_lds(                         \
    (const __attribute__((address_space(1))) void*)(gp),                       \
    (__attribute__((address_space(3))) void*)(lp), 16, 0, 0)

#define MFMA16(a, b, c) __builtin_amdgcn_mfma_f32_16x16x32_bf16((a), (b), (c), 0, 0, 0)

// ---------------------------------------------------------------------------
// Pre-pass: fp32 -> single bf16 plane (elementwise).
// ---------------------------------------------------------------------------
__global__ __launch_bounds__(256) void cast_x(const float* __restrict__ src,
                                              u16* __restrict__ dst)
{
  int i = blockIdx.x * 256 + threadIdx.x;
  float4 v = ((const float4*)src)[i];
  ushort4 hh;
  hh.x = f2bf(v.x); hh.y = f2bf(v.y); hh.z = f2bf(v.z); hh.w = f2bf(v.w);
  ((ushort4*)dst)[i] = hh;
}

// ---------------------------------------------------------------------------
// Pre-pass: transpose + split W [2048 x N] -> BT planes [nofs+n][2048] bf16.
// ---------------------------------------------------------------------------
__global__ __launch_bounds__(256) void tsplit_w(const float* __restrict__ W, int N,
                                                u16* __restrict__ BTh,
                                                u16* __restrict__ BTl, int nofs)
{
  __shared__ float t[64][68];
  const int nt = blockIdx.x * 64, kt = blockIdx.y * 64;
  const int tid = threadIdx.x;
  const int c4 = (tid & 15) * 4, r0 = tid >> 4;
  #pragma unroll
  for (int i = 0; i < 4; i++) {
    int r = r0 + i * 16;
    float4 v = *(const float4*)(&W[(size_t)(kt + r) * N + nt + c4]);
    t[c4 + 0][r] = v.x; t[c4 + 1][r] = v.y; t[c4 + 2][r] = v.z; t[c4 + 3][r] = v.w;
  }
  __syncthreads();
  #pragma unroll
  for (int i = 0; i < 4; i++) {
    int rr = r0 + i * 16;
    float4 v = *(const float4*)(&t[rr][c4]);
    ushort4 hh, ll;
    split_bf16(v.x, hh.x, ll.x);
    split_bf16(v.y, hh.y, ll.y);
    split_bf16(v.z, hh.z, ll.z);
    split_bf16(v.w, hh.w, ll.w);
    size_t o = (size_t)(nofs + nt + rr) * 2048 + kt + c4;
    *(ushort4*)(&BTh[o]) = hh;
    *(ushort4*)(&BTl[o]) = ll;
  }
}

// ---------------------------------------------------------------------------
// MFMA GEMM main loops (128x128 tile, BK=32, 4 waves).
// gemm_main2: A single bf16 plane, B split hi/lo  -> C = A*Bh + A*Bl
// gemm_main1: A single, B single                  -> C = A*B
// A [M][2048] row-major; B planes [N][2048] row-major (= W^T).
// ---------------------------------------------------------------------------
__device__ __forceinline__ void gemm_main2(
    const u16* __restrict__ A,
    const u16* __restrict__ Bh, const u16* __restrict__ Bl,
    int mtile, int ntile,
    u16* sA, u16* sBh, u16* sBl,
    f32x4 acc[4][4])
{
  const int tid  = threadIdx.x;
  const int lane = tid & 63;
  const int w    = tid >> 6;
  const int wr = (w >> 1) * 64, wc = (w & 1) * 64;
  const int fr = lane & 15, fk = (lane >> 4) * 8;

  const int r0 = tid >> 2, c0 = (tid & 3) * 8;
  const size_t a0 = (size_t)(mtile + r0) * 2048 + c0;
  const size_t a1 = (size_t)(mtile + r0 + 64) * 2048 + c0;
  const size_t b0 = (size_t)(ntile + r0) * 2048 + c0;
  const size_t b1 = (size_t)(ntile + r0 + 64) * 2048 + c0;
  const int d0 = tid * 8, d1 = tid * 8 + 2048;

  for (int kt = 0; kt < 2048; kt += 32) {
    GL16(A  + a0 + kt, sA  + d0);
    GL16(A  + a1 + kt, sA  + d1);
    GL16(Bh + b0 + kt, sBh + d0);
    GL16(Bh + b1 + kt, sBh + d1);
    GL16(Bl + b0 + kt, sBl + d0);
    GL16(Bl + b1 + kt, sBl + d1);
    __syncthreads();

    s16x8 bhf[4], blf[4];
    #pragma unroll
    for (int ni = 0; ni < 4; ni++) {
      bhf[ni] = *(const s16x8*)(&sBh[(wc + ni * 16 + fr) * 32 + fk]);
      blf[ni] = *(const s16x8*)(&sBl[(wc + ni * 16 + fr) * 32 + fk]);
    }
    #pragma unroll
    for (int mi = 0; mi < 4; mi++) {
      s16x8 a = *(const s16x8*)(&sA[(wr + mi * 16 + fr) * 32 + fk]);
      #pragma unroll
      for (int ni = 0; ni < 4; ni++) {
        f32x4 c = acc[mi][ni];
        c = MFMA16(a, bhf[ni], c);
        c = MFMA16(a, blf[ni], c);
        acc[mi][ni] = c;
      }
    }
    __syncthreads();
  }
}

__device__ __forceinline__ void gemm_main1(
    const u16* __restrict__ A, const u16* __restrict__ B,
    int mtile, int ntile,
    u16* sA, u16* sB,
    f32x4 acc[4][4])
{
  const int tid  = threadIdx.x;
  const int lane = tid & 63;
  const int w    = tid >> 6;
  const int wr = (w >> 1) * 64, wc = (w & 1) * 64;
  const int fr = lane & 15, fk = (lane >> 4) * 8;

  const int r0 = tid >> 2, c0 = (tid & 3) * 8;
  const size_t a0 = (size_t)(mtile + r0) * 2048 + c0;
  const size_t a1 = (size_t)(mtile + r0 + 64) * 2048 + c0;
  const size_t b0 = (size_t)(ntile + r0) * 2048 + c0;
  const size_t b1 = (size_t)(ntile + r0 + 64) * 2048 + c0;
  const int d0 = tid * 8, d1 = tid * 8 + 2048;

  for (int kt = 0; kt < 2048; kt += 32) {
    GL16(A + a0 + kt, sA + d0);
    GL16(A + a1 + kt, sA + d1);
    GL16(B + b0 + kt, sB + d0);
    GL16(B + b1 + kt, sB + d1);
    __syncthreads();

    s16x8 bf[4];
    #pragma unroll
    for (int ni = 0; ni < 4; ni++)
      bf[ni] = *(const s16x8*)(&sB[(wc + ni * 16 + fr) * 32 + fk]);
    #pragma unroll
    for (int mi = 0; mi < 4; mi++) {
      s16x8 a = *(const s16x8*)(&sA[(wr + mi * 16 + fr) * 32 + fk]);
      #pragma unroll
      for (int ni = 0; ni < 4; ni++)
        acc[mi][ni] = MFMA16(a, bf[ni], acc[mi][ni]);
    }
    __syncthreads();
  }
}

// ---------------------------------------------------------------------------
// Fused QKV projection + in-register RoPE + bf16 plane emission.
// N-tiles [0,2048): Q -> roped+scaled bf16 hi/lo planes [m][2048]
// N-tiles [2048,2560): K -> roped fp32 k-cache + bf16 hi/lo planes [bh][s][d]
// N-tiles [2560,3072): V -> fp32 v-cache + bf16 transposed plane [bh][d][s]
// ---------------------------------------------------------------------------
#define L2_10K 13.28771238f   // log2(10000)

__global__ __launch_bounds__(256, 2) void gemm_qkv(
    const u16* __restrict__ A,
    const u16* __restrict__ Bh, const u16* __restrict__ Bl,
    u16* __restrict__ Qh, u16* __restrict__ Ql,
    float* __restrict__ kout, float* __restrict__ vout,
    u16* __restrict__ Kh, u16* __restrict__ Kl, u16* __restrict__ Vt)
{
  __shared__ __align__(16) u16 sA[128 * 32], sBh[128 * 32], sBl[128 * 32];
  const int ntile = blockIdx.x * 128, mtile = blockIdx.y * 128;
  f32x4 acc[4][4] = {};
  gemm_main2(A, Bh, Bl, mtile, ntile, sA, sBh, sBl, acc);

  const int lane = threadIdx.x & 63, w = threadIdx.x >> 6;
  const int wr = (w >> 1) * 64, wc = (w & 1) * 64;
  const int orow = (lane >> 4) * 4, ocol = lane & 15;

  if (ntile < 2048) {
    float inv[2];
    #pragma unroll
    for (int nj = 0; nj < 2; nj++)
      inv[nj] = exp2f((float)(nj * 16 + ocol) * (-L2_10K / 32.0f));
    #pragma unroll
    for (int mi = 0; mi < 4; mi++)
      #pragma unroll
      for (int r = 0; r < 4; r++) {
        int m = mtile + wr + mi * 16 + orow + r;
        int s = m & 511;
        #pragma unroll
        for (int nj = 0; nj < 2; nj++) {
          float th = (float)s * inv[nj];
          float sn, cs; sincosf(th, &sn, &cs);
          float a0 = acc[mi][nj][r]     * 0.125f;   // scale folded into Q
          float a1 = acc[mi][nj + 2][r] * 0.125f;
          float q0 = a0 * cs - a1 * sn;
          float q1 = a1 * cs + a0 * sn;
          size_t o0 = (size_t)m * 2048 + ntile + wc + nj * 16 + ocol;
          u16 hh, ll;
          split_bf16(q0, hh, ll); Qh[o0] = hh;      Ql[o0] = ll;
          split_bf16(q1, hh, ll); Qh[o0 + 32] = hh; Ql[o0 + 32] = ll;
        }
      }
  } else if (ntile < 2560) {
    float inv[2];
    #pragma unroll
    for (int nj = 0; nj < 2; nj++)
      inv[nj] = exp2f((float)(nj * 16 + ocol) * (-L2_10K / 32.0f));
    #pragma unroll
    for (int mi = 0; mi < 4; mi++)
      #pragma unroll
      for (int r = 0; r < 4; r++) {
        int m = mtile + wr + mi * 16 + orow + r;
        int bb = m >> 9, s = m & 511;
        #pragma unroll
        for (int nj = 0; nj < 2; nj++) {
          int np = ntile + wc + nj * 16 + ocol - 2048;
          int hk = np >> 6, d = np & 63;            // d in [0,32)
          float th = (float)s * inv[nj];
          float sn, cs; sincosf(th, &sn, &cs);
          float a0 = acc[mi][nj][r];
          float a1 = acc[mi][nj + 2][r];
          float k0 = a0 * cs - a1 * sn;
          float k1 = a1 * cs + a0 * sn;
          size_t o = ((size_t)(bb * 8 + hk) * 512 + s) * 64 + d;
          kout[o] = k0; kout[o + 32] = k1;
          u16 hh, ll;
          split_bf16(k0, hh, ll); Kh[o] = hh;      Kl[o] = ll;
          split_bf16(k1, hh, ll); Kh[o + 32] = hh; Kl[o + 32] = ll;
        }
      }
  } else {
    #pragma unroll
    for (int mi = 0; mi < 4; mi++)
      #pragma unroll
      for (int ni = 0; ni < 4; ni++) {
        int np = ntile + wc + ni * 16 + ocol - 2560;
        int hk = np >> 6, d = np & 63;
        int m0 = mtile + wr + mi * 16 + orow;
        int bb = m0 >> 9, s0 = m0 & 511;            // multiple of 4
        ushort4 pk;
        #pragma unroll
        for (int r = 0; r < 4; r++) {
          float v = acc[mi][ni][r];
          vout[((size_t)(bb * 8 + hk) * 512 + s0 + r) * 64 + d] = v;
          ((u16*)&pk)[r] = f2bf(v);
        }
        *(ushort4*)(&Vt[((size_t)(bb * 8 + hk) * 64 + d) * 512 + s0]) = pk;
      }
  }
}

// ---------------------------------------------------------------------------
// Output projection: out = Ao[4096,2048] @ Wo, single bf16 x single bf16.
// ---------------------------------------------------------------------------
__global__ __launch_bounds__(256, 2) void gemm_out(
    const u16* __restrict__ A, const u16* __restrict__ B,
    float* __restrict__ Cout)
{
  __shared__ __align__(16) u16 sA[128 * 32], sB[128 * 32];
  const int ntile = blockIdx.x * 128, mtile = blockIdx.y * 128;
  f32x4 acc[4][4] = {};
  gemm_main1(A, B, mtile, ntile, sA, sB, acc);

  const int lane = threadIdx.x & 63, w = threadIdx.x >> 6;
  const int wr = (w >> 1) * 64, wc = (w & 1) * 64;
  const int orow = (lane >> 4) * 4, ocol = lane & 15;
  #pragma unroll
  for (int mi = 0; mi < 4; mi++)
    #pragma unroll
    for (int r = 0; r < 4; r++) {
      int m = mtile + wr + mi * 16 + orow + r;
      #pragma unroll
      for (int ni = 0; ni < 4; ni++)
        Cout[(size_t)m * 2048 + ntile + wc + ni * 16 + ocol] = acc[mi][ni][r];
    }
}

// ---------------------------------------------------------------------------
// MFMA flash attention (unchanged structure from R4; epilogue emits a single
// bf16 plane). QK^T = 3-term split bf16; PV = single bf16.
// ---------------------------------------------------------------------------
__global__ __launch_bounds__(256, 2)
void attn(const u16* __restrict__ Qh, const u16* __restrict__ Ql,
          const u16* __restrict__ Kh, const u16* __restrict__ Kl,
          const u16* __restrict__ Vt,
          u16* __restrict__ Ao)
{
  __shared__ __align__(16) u16 sKh[4096], sKl[4096], sVt[4096];  // 8 KB each
  __shared__ __align__(16) u16 sP[4][1024];                      // 2 KB/wave

  const int qt = blockIdx.x, h = blockIdx.y, bb = blockIdx.z;
  const int hk = h >> 2, bh = bb * 8 + hk;
  const int tid = threadIdx.x, lane = tid & 63, w = tid >> 6;
  const int fr = lane & 15, fg = lane >> 4;

  const int qrow = bb * 512 + qt * 64 + w * 16 + fr;
  const size_t qoff = (size_t)qrow * 2048 + h * 64 + fg * 8;
  const s16x8 qh0 = *(const s16x8*)(Qh + qoff);
  const s16x8 qh1 = *(const s16x8*)(Qh + qoff + 32);
  const s16x8 ql0 = *(const s16x8*)(Ql + qoff);
  const s16x8 ql1 = *(const s16x8*)(Ql + qoff + 32);

  f32x4 oacc[4] = {};
  float m_r[4] = {-1e30f, -1e30f, -1e30f, -1e30f};
  float l_r[4] = {};

  const size_t kbase = (size_t)bh * 512 * 64;   // K planes [bh][s][d]
  const size_t vbase = (size_t)bh * 64 * 512;   // Vt plane [bh][d][s]

  for (int j = 0; j <= qt; j++) {
    __syncthreads();
    #pragma unroll
    for (int p = 0; p < 2; p++) {
      int s = tid + p * 256;
      int row = s >> 3, c8 = (s & 7) ^ (row & 7);   // pre-swizzled source col
      GL16(Kh + kbase + (size_t)(j * 64 + row) * 64 + c8 * 8, sKh + s * 8);
      GL16(Kl + kbase + (size_t)(j * 64 + row) * 64 + c8 * 8, sKl + s * 8);
      GL16(Vt + vbase + (size_t)row * 512 + j * 64 + c8 * 8,  sVt + s * 8);
    }
    __syncthreads();

    // ---- S = (Q*scale) K^T, 3-term split ----
    f32x4 sacc[4] = {};
    #pragma unroll
    for (int ni = 0; ni < 4; ni++) {
      #pragma unroll
      for (int ks = 0; ks < 2; ks++) {
        int row = ni * 16 + fr;
        int byte = row * 128 + ((fg * 16 + ks * 64) ^ ((row & 7) << 4));
        s16x8 kh = *(const s16x8*)((const char*)sKh + byte);
        s16x8 kl = *(const s16x8*)((const char*)sKl + byte);
        s16x8 qa = ks ? qh1 : qh0;
        s16x8 qb = ks ? ql1 : ql0;
        f32x4 c = sacc[ni];
        c = MFMA16(qa, kh, c);
        c = MFMA16(qa, kl, c);
        c = MFMA16(qb, kh, c);
        sacc[ni] = c;
      }
    }

    // ---- causal mask + online softmax ----
    const int rowg0 = qt * 64 + w * 16 + fg * 4;
    #pragma unroll
    for (int r = 0; r < 4; r++) {
      float mx = -1e30f;
      #pragma unroll
      for (int ni = 0; ni < 4; ni++) {
        int col = j * 64 + ni * 16 + fr;
        float v = (col <= rowg0 + r) ? sacc[ni][r] : -1e30f;
        sacc[ni][r] = v;
        mx = fmaxf(mx, v);
      }
      mx = fmaxf(mx, __shfl_xor(mx, 1));
      mx = fmaxf(mx, __shfl_xor(mx, 2));
      mx = fmaxf(mx, __shfl_xor(mx, 4));
      mx = fmaxf(mx, __shfl_xor(mx, 8));
      float mnew = fmaxf(m_r[r], mx);
      float sc = __expf(m_r[r] - mnew);
      m_r[r] = mnew;
      float ls = 0.0f;
      #pragma unroll
      for (int ni = 0; ni < 4; ni++) {
        float p = __expf(sacc[ni][r] - mnew);
        sacc[ni][r] = p;
        ls += p;
      }
      ls += __shfl_xor(ls, 1);
      ls += __shfl_xor(ls, 2);
      ls += __shfl_xor(ls, 4);
      ls += __shfl_xor(ls, 8);
      l_r[r] = l_r[r] * sc + ls;
      #pragma unroll
      for (int nd = 0; nd < 4; nd++) oacc[nd][r] *= sc;
    }

    // ---- P -> per-wave LDS strip (bf16, swizzled) ----
    u16* pbuf = sP[w];
    #pragma unroll
    for (int ni = 0; ni < 4; ni++)
      #pragma unroll
      for (int r = 0; r < 4; r++) {
        int prow = fg * 4 + r, pcol = ni * 16 + fr;
        int byte = prow * 128 + ((pcol * 2) ^ ((prow & 7) << 4));
        *(u16*)((char*)pbuf + byte) = f2bf(sacc[ni][r]);
      }

    // ---- O += P V ----
    #pragma unroll
    for (int ks = 0; ks < 2; ks++) {
      int pbyte = fr * 128 + ((fg * 16 + ks * 64) ^ ((fr & 7) << 4));
      s16x8 pa = *(const s16x8*)((const char*)pbuf + pbyte);
      #pragma unroll
      for (int nd = 0; nd < 4; nd++) {
        int vrow = nd * 16 + fr;
        int vbyte = vrow * 128 + ((fg * 16 + ks * 64) ^ ((vrow & 7) << 4));
        s16x8 vb = *(const s16x8*)((const char*)sVt + vbyte);
        oacc[nd] = MFMA16(pa, vb, oacc[nd]);
      }
    }
  }

  // ---- epilogue: normalize, emit single bf16 plane [m][2048] ----
  const size_t obase = (size_t)(bb * 512 + qt * 64 + w * 16 + fg * 4) * 2048 + h * 64;
  #pragma unroll
  for (int r = 0; r < 4; r++) {
    float inv = 1.0f / l_r[r];
    #pragma unroll
    for (int nd = 0; nd < 4; nd++)
      Ao[obase + (size_t)r * 2048 + nd * 16 + fr] = f2bf(oacc[nd][r] * inv);
  }
}

// ---------------------------------------------------------------------------
extern "C" void kernel_launch(void* const* d_in, const int* in_sizes, int n_in,
                              void* d_out, int out_size, void* d_ws, size_t ws_size,
                              hipStream_t stream)
{
  const float* x  = (const float*)d_in[0];
  const float* Wq = (const float*)d_in[1];
  const float* Wk = (const float*)d_in[2];
  const float* Wv = (const float*)d_in[3];
  const float* Wo = (const float*)d_in[4];

  float* out  = (float*)d_out;                 // [B,S,2048]
  float* kout = out + 8388608;                 // k cache [B,8,S,64]
  float* vout = out + 10485760;                // v cache [B,8,S,64]

  // Workspace layout (84 MiB):
  //  [0,16M)        xbf single plane -> Ao single plane (alias)
  //  [16M,40M)      Wqkv split planes; Wo split planes alias the front
  //  [40M,72M)      Qh/Ql roped+scaled bf16 planes
  //  [72M,80M)      Kh/Kl roped bf16 planes
  //  [80M,84M)      Vt transposed bf16 plane
  uint8_t* wsb = (uint8_t*)d_ws;
  u16* xbf = (u16*)(wsb + 0);
  u16* Ao  = xbf;                              // alias: x dead after gemm_qkv
  u16* Wqh = (u16*)(wsb + 16777216);           // [3072][2048]
  u16* Wql = (u16*)(wsb + 29360128);
  u16* Woh = (u16*)(wsb + 16777216);           // alias: Wqkv dead after gemm_qkv
  u16* Wol = (u16*)(wsb + 25165824);
  u16* Qhp = (u16*)(wsb + 41943040);
  u16* Qlp = (u16*)(wsb + 58720256);
  u16* Khp = (u16*)(wsb + 75497472);
  u16* Klp = (u16*)(wsb + 79691776);
  u16* Vtp = (u16*)(wsb + 83886080);

  cast_x<<<8192, 256, 0, stream>>>(x, xbf);
  tsplit_w<<<dim3(32, 32), 256, 0, stream>>>(Wq, 2048, Wqh, Wql, 0);
  tsplit_w<<<dim3(8, 32), 256, 0, stream>>>(Wk, 512, Wqh, Wql, 2048);
  tsplit_w<<<dim3(8, 32), 256, 0, stream>>>(Wv, 512, Wqh, Wql, 2560);
  gemm_qkv<<<dim3(24, 32), 256, 0, stream>>>(xbf, Wqh, Wql,
                                             Qhp, Qlp, kout, vout, Khp, Klp, Vtp);
  tsplit_w<<<dim3(32, 32), 256, 0, stream>>>(Wo, 2048, Woh, Wol, 0);
  attn<<<dim3(8, 32, 8), 256, 0, stream>>>(Qhp, Qlp, Khp, Klp, Vtp, Ao);
  gemm_out<<<dim3(16, 32), 256, 0, stream>>>(Ao, Woh, out);
}